// Round 1
// baseline (656.855 us; speedup 1.0000x reference)
//
#include <hip/hip_runtime.h>
#include <hip/hip_bf16.h>
#include <math.h>

#define BB 8
#define C1D 384
#define C2D 192
#define LDIM 4096
#define ADIM 384
#define NH 8
#define DHD 48
#define NCHUNK 32
#define KV_LCH 16
#define LN_EPS 1e-5f

// ---------------- GEMM: Out[b,l,a] = scl*(sum_c X[b,c,l]*W[c,a] + bias[a]) ----------------
__global__ __launch_bounds__(256) void gemm_xtw(
    const float* __restrict__ X,   // [B, Cin, L]
    const float* __restrict__ Wt,  // [Cin, A]
    const float* __restrict__ bias,// [A]
    float* __restrict__ Out,       // [B, L, A]
    int Cin, float scl)
{
    __shared__ float Xs[16][64];
    __shared__ float Ws[16][64];
    int b = blockIdx.z;
    int l0 = blockIdx.x * 64;
    int a0 = blockIdx.y * 64;
    int t = threadIdx.x;
    int tx = t & 15, ty = t >> 4;
    const float* Xb = X + (size_t)b * Cin * LDIM;
    float acc[4][4] = {};
    for (int c0 = 0; c0 < Cin; c0 += 16) {
#pragma unroll
        for (int i = 0; i < 4; ++i) {
            int idx = t + i * 256;
            int kc = idx >> 6, m = idx & 63;
            Xs[kc][m] = Xb[(size_t)(c0 + kc) * LDIM + l0 + m];
            Ws[kc][m] = Wt[(size_t)(c0 + kc) * ADIM + a0 + m];
        }
        __syncthreads();
#pragma unroll
        for (int kc = 0; kc < 16; ++kc) {
            float xr[4], wr[4];
#pragma unroll
            for (int i = 0; i < 4; ++i) xr[i] = Xs[kc][ty * 4 + i];
#pragma unroll
            for (int j = 0; j < 4; ++j) wr[j] = Ws[kc][tx * 4 + j];
#pragma unroll
            for (int i = 0; i < 4; ++i)
#pragma unroll
                for (int j = 0; j < 4; ++j)
                    acc[i][j] += xr[i] * wr[j];
        }
        __syncthreads();
    }
    float* Ob = Out + (size_t)b * LDIM * ADIM;
#pragma unroll
    for (int i = 0; i < 4; ++i) {
        int l = l0 + ty * 4 + i;
        int a = a0 + tx * 4;
        float4 v;
        v.x = (acc[i][0] + bias[a + 0]) * scl;
        v.y = (acc[i][1] + bias[a + 1]) * scl;
        v.z = (acc[i][2] + bias[a + 2]) * scl;
        v.w = (acc[i][3] + bias[a + 3]) * scl;
        *(float4*)(Ob + (size_t)l * ADIM + a) = v;
    }
}

// ---------------- column softmax stats (over L) ----------------
__global__ __launch_bounds__(384) void col_partial(const float* __restrict__ K,
                                                   float* __restrict__ pm, float* __restrict__ ps)
{
    int b = blockIdx.y, ch = blockIdx.x, a = threadIdx.x;
    const int CL = LDIM / NCHUNK;
    const float* Kb = K + (size_t)b * LDIM * ADIM + (size_t)ch * CL * ADIM + a;
    float m = -1e30f;
    for (int l = 0; l < CL; ++l) m = fmaxf(m, Kb[(size_t)l * ADIM]);
    float s = 0.f;
    for (int l = 0; l < CL; ++l) s += __expf(Kb[(size_t)l * ADIM] - m);
    pm[(b * NCHUNK + ch) * ADIM + a] = m;
    ps[(b * NCHUNK + ch) * ADIM + a] = s;
}

__global__ __launch_bounds__(384) void col_combine(const float* __restrict__ pm, const float* __restrict__ ps,
                                                   float* __restrict__ fm, float* __restrict__ fs)
{
    int b = blockIdx.x, a = threadIdx.x;
    float m = -1e30f;
    for (int c = 0; c < NCHUNK; ++c) m = fmaxf(m, pm[(b * NCHUNK + c) * ADIM + a]);
    float s = 0.f;
    for (int c = 0; c < NCHUNK; ++c) s += ps[(b * NCHUNK + c) * ADIM + a] * __expf(pm[(b * NCHUNK + c) * ADIM + a] - m);
    fm[b * ADIM + a] = m;
    fs[b * ADIM + a] = s;
}

// ---------------- kv[b,h,d,e] = sum_l softmax(K)[l,d] * V[l,e] ----------------
__global__ __launch_bounds__(256) void kv_accum(const float* __restrict__ K, const float* __restrict__ V,
                                                const float* __restrict__ fm, const float* __restrict__ fs,
                                                float* __restrict__ kvg)
{
    __shared__ float Ps[64][48];
    __shared__ float Vs[64][48];
    __shared__ float ml[48], isl[48];
    int b = blockIdx.z, h = blockIdx.y, lc = blockIdx.x;
    int t = threadIdx.x;
    if (t < 48) {
        ml[t]  = fm[b * ADIM + h * DHD + t];
        isl[t] = 1.f / fs[b * ADIM + h * DHD + t];
    }
    __syncthreads();
    int dd[9], ee[9];
#pragma unroll
    for (int i = 0; i < 9; ++i) { int p = t + i * 256; dd[i] = p / 48; ee[i] = p % 48; }
    float acc[9] = {};
    int lbase = lc * (LDIM / KV_LCH);
    for (int lt = 0; lt < (LDIM / KV_LCH); lt += 64) {
#pragma unroll
        for (int i = 0; i < 12; ++i) {
            int idx = t + i * 256;
            int ll = idx / 48, d = idx % 48;
            size_t g = (size_t)b * LDIM * ADIM + (size_t)(lbase + lt + ll) * ADIM + h * DHD + d;
            Ps[ll][d] = __expf(K[g] - ml[d]) * isl[d];
            Vs[ll][d] = V[g];
        }
        __syncthreads();
        for (int l = 0; l < 64; ++l) {
#pragma unroll
            for (int i = 0; i < 9; ++i)
                acc[i] += Ps[l][dd[i]] * Vs[l][ee[i]];
        }
        __syncthreads();
    }
    float* kvb = kvg + ((size_t)b * NH + h) * DHD * DHD;
#pragma unroll
    for (int i = 0; i < 9; ++i) atomicAdd(&kvb[t + i * 256], acc[i]);
}

// ---------------- ctx[b,l,h*48+e] = sum_d Q[b,l,h*48+d] * kv[b,h,d,e] ----------------
__global__ __launch_bounds__(256) void ctx_kernel(const float* __restrict__ Q, const float* __restrict__ kvg,
                                                  float* __restrict__ CTX)
{
    __shared__ float Qs[64][48];
    __shared__ float kvs[48][48];
    int b = blockIdx.z, h = blockIdx.y, l0 = blockIdx.x * 64;
    int t = threadIdx.x;
    const float* kvb = kvg + ((size_t)b * NH + h) * DHD * DHD;
#pragma unroll
    for (int i = 0; i < 9; ++i) {
        int p = t + i * 256;
        kvs[p / 48][p % 48] = kvb[p];
    }
#pragma unroll
    for (int i = 0; i < 12; ++i) {
        int idx = t + i * 256;
        int ll = idx / 48, d = idx % 48;
        Qs[ll][d] = Q[(size_t)b * LDIM * ADIM + (size_t)(l0 + ll) * ADIM + h * DHD + d];
    }
    __syncthreads();
#pragma unroll
    for (int i = 0; i < 12; ++i) {
        int idx = t + i * 256;
        int ll = idx / 48, e = idx % 48;
        float s = 0.f;
#pragma unroll
        for (int d = 0; d < 48; ++d) s += Qs[ll][d] * kvs[d][e];
        CTX[(size_t)b * LDIM * ADIM + (size_t)(l0 + ll) * ADIM + h * DHD + e] = s;
    }
}

// ---------------- OUT[b,l,c] = sum_a CTX[b,l,a]*Wo[a,c] + bo[c] ----------------
__global__ __launch_bounds__(256) void gemm_out(const float* __restrict__ CTX, const float* __restrict__ Wo,
                                                const float* __restrict__ bo, float* __restrict__ OUT)
{
    __shared__ float Cs[64][17];
    __shared__ float Ws[16][64];
    int b = blockIdx.z;
    int l0 = blockIdx.x * 64;
    int c0 = blockIdx.y * 64;
    int t = threadIdx.x;
    int tx = t & 15, ty = t >> 4;
    float acc[4][4] = {};
    for (int a0 = 0; a0 < ADIM; a0 += 16) {
#pragma unroll
        for (int i = 0; i < 4; ++i) {
            int idx = t + i * 256;
            int ll = idx >> 4, ka = idx & 15;
            Cs[ll][ka] = CTX[(size_t)b * LDIM * ADIM + (size_t)(l0 + ll) * ADIM + a0 + ka];
            int kc = idx >> 6, cc = idx & 63;
            Ws[kc][cc] = Wo[(size_t)(a0 + kc) * C1D + c0 + cc];
        }
        __syncthreads();
#pragma unroll
        for (int kc = 0; kc < 16; ++kc) {
            float xr[4], wr[4];
#pragma unroll
            for (int i = 0; i < 4; ++i) xr[i] = Cs[ty * 4 + i][kc];
#pragma unroll
            for (int j = 0; j < 4; ++j) wr[j] = Ws[kc][tx * 4 + j];
#pragma unroll
            for (int i = 0; i < 4; ++i)
#pragma unroll
                for (int j = 0; j < 4; ++j)
                    acc[i][j] += xr[i] * wr[j];
        }
        __syncthreads();
    }
#pragma unroll
    for (int i = 0; i < 4; ++i) {
        int l = l0 + ty * 4 + i;
        int c = c0 + tx * 4;
        float4 v;
        v.x = acc[i][0] + bo[c + 0];
        v.y = acc[i][1] + bo[c + 1];
        v.z = acc[i][2] + bo[c + 2];
        v.w = acc[i][3] + bo[c + 3];
        *(float4*)(OUT + (size_t)b * LDIM * C1D + (size_t)l * C1D + c) = v;
    }
}

// ---------------- residual + LayerNorm + transpose store ----------------
__global__ __launch_bounds__(256) void ln_store(const float* __restrict__ OUT, const float* __restrict__ x1,
                                                const float* __restrict__ gamma, const float* __restrict__ beta,
                                                float* __restrict__ Y)
{
    __shared__ float Ts[32][C1D + 1];
    __shared__ float mus[32], rss[32];
    int b = blockIdx.y, l0 = blockIdx.x * 32;
    int t = threadIdx.x;
    for (int idx = t; idx < 32 * C1D; idx += 256) {
        int li = idx / C1D, c = idx % C1D;
        Ts[li][c] = OUT[(size_t)b * LDIM * C1D + (size_t)(l0 + li) * C1D + c];
    }
    __syncthreads();
    for (int idx = t; idx < 32 * C1D; idx += 256) {
        int c = idx / 32, li = idx % 32;
        Ts[li][c] += x1[(size_t)b * C1D * LDIM + (size_t)c * LDIM + l0 + li];
    }
    __syncthreads();
    {
        int li = t >> 3, sub = t & 7;
        float sm = 0.f, sq = 0.f;
        for (int c = sub; c < C1D; c += 8) { float v = Ts[li][c]; sm += v; sq += v * v; }
#pragma unroll
        for (int o = 1; o < 8; o <<= 1) { sm += __shfl_xor(sm, o, 64); sq += __shfl_xor(sq, o, 64); }
        if (sub == 0) {
            float mu = sm / C1D;
            float var = sq / C1D - mu * mu;
            mus[li] = mu;
            rss[li] = rsqrtf(var + LN_EPS);
        }
    }
    __syncthreads();
    for (int idx = t; idx < 32 * C1D; idx += 256) {
        int c = idx / 32, li = idx % 32;
        float v = (Ts[li][c] - mus[li]) * rss[li] * gamma[c] + beta[c];
        Y[(size_t)b * C1D * LDIM + (size_t)c * LDIM + l0 + li] = v;
    }
}

extern "C" void kernel_launch(void* const* d_in, const int* in_sizes, int n_in,
                              void* d_out, int out_size, void* d_ws, size_t ws_size,
                              hipStream_t stream) {
    const float* x1    = (const float*)d_in[0];
    const float* x2    = (const float*)d_in[1];
    const float* Wq    = (const float*)d_in[2];
    const float* bq    = (const float*)d_in[3];
    const float* Wk    = (const float*)d_in[4];
    const float* bk    = (const float*)d_in[5];
    const float* Wv    = (const float*)d_in[6];
    const float* bv    = (const float*)d_in[7];
    const float* Wo    = (const float*)d_in[8];
    const float* bo    = (const float*)d_in[9];
    const float* gamma = (const float*)d_in[10];
    const float* beta  = (const float*)d_in[11];
    float* out = (float*)d_out;
    float* ws  = (float*)d_ws;

    size_t NBL = (size_t)BB * LDIM * ADIM;  // 12.58M floats
    float* Qb = ws;
    float* Kb = ws + NBL;
    float* Vb = ws + 2 * NBL;
    float* pm = ws + 3 * NBL;
    float* ps = pm + (size_t)BB * NCHUNK * ADIM;
    float* fm = ps + (size_t)BB * NCHUNK * ADIM;
    float* fs = fm + (size_t)BB * ADIM;
    float* kvb = fs + (size_t)BB * ADIM;
    float* CTX = Vb;  // V consumed by kv_accum before ctx_kernel writes here
    float* OUT = Kb;  // K consumed by kv_accum before gemm_out writes here

    float inv_scale = 1.0f / powf((float)DHD, 0.25f);

    dim3 g1(LDIM / 64, ADIM / 64, BB);
    gemm_xtw<<<g1, 256, 0, stream>>>(x1, Wq, bq, Qb, C1D, inv_scale);
    gemm_xtw<<<g1, 256, 0, stream>>>(x2, Wk, bk, Kb, C2D, inv_scale);
    gemm_xtw<<<g1, 256, 0, stream>>>(x2, Wv, bv, Vb, C2D, 1.0f);

    col_partial<<<dim3(NCHUNK, BB), 384, 0, stream>>>(Kb, pm, ps);
    col_combine<<<BB, 384, 0, stream>>>(pm, ps, fm, fs);

    hipMemsetAsync(kvb, 0, (size_t)BB * NH * DHD * DHD * sizeof(float), stream);
    kv_accum<<<dim3(KV_LCH, NH, BB), 256, 0, stream>>>(Kb, Vb, fm, fs, kvb);

    ctx_kernel<<<dim3(LDIM / 64, NH, BB), 256, 0, stream>>>(Qb, kvb, CTX);
    gemm_out<<<g1, 256, 0, stream>>>(CTX, Wo, bo, OUT);
    ln_store<<<dim3(LDIM / 32, BB), 256, 0, stream>>>(OUT, x1, gamma, beta, out);
}

// Round 2
// 266.185 us; speedup vs baseline: 2.4677x; 2.4677x over previous
//
#include <hip/hip_runtime.h>
#include <hip/hip_bf16.h>
#include <math.h>

#define BB 8
#define C1D 384
#define C2D 192
#define LDIM 4096
#define ADIM 384
#define NH 8
#define DHD 48
#define NCHUNK 32
#define KV_LCH 16
#define KVT 576
#define LN_EPS 1e-5f

typedef short s8v __attribute__((ext_vector_type(8)));
typedef float f4v __attribute__((ext_vector_type(4)));

__device__ __forceinline__ unsigned short f2bf(float f) {
    unsigned u = __builtin_bit_cast(unsigned, f);
    unsigned r = (u + 0x7FFFu + ((u >> 16) & 1u)) >> 16;
    return (unsigned short)r;
}

__device__ __forceinline__ void gload16(const void* g, void* l) {
    __builtin_amdgcn_global_load_lds((const __attribute__((address_space(1))) void*)g,
                                     (__attribute__((address_space(3))) void*)l, 16, 0, 0);
}

// ---------- transpose fp32 [bz][R][Cols] -> bf16 [bz][Cols][R] ----------
__global__ __launch_bounds__(256) void transpose_cvt(const float* __restrict__ in,
                                                     unsigned short* __restrict__ out,
                                                     int R, int Cols)
{
    __shared__ float T[32][33];
    int b = blockIdx.z;
    int c0 = blockIdx.x * 32, r0 = blockIdx.y * 32;
    const float* ib = in + (size_t)b * R * Cols;
    unsigned short* ob = out + (size_t)b * R * Cols;
    int t = threadIdx.x;
#pragma unroll
    for (int i = 0; i < 4; ++i) {
        int idx = t + i * 256;
        int rr = idx >> 5, cc = idx & 31;
        T[rr][cc] = ib[(size_t)(r0 + rr) * Cols + c0 + cc];
    }
    __syncthreads();
#pragma unroll
    for (int i = 0; i < 2; ++i) {
        int idx = t + i * 256;
        int cc = idx >> 4, rp = (idx & 15) * 2;
        unsigned val = (unsigned)f2bf(T[rp][cc]) | ((unsigned)f2bf(T[rp + 1][cc]) << 16);
        *(unsigned*)&ob[(size_t)(c0 + cc) * R + r0 + rp] = val;
    }
}

// ---------- bf16 MFMA GEMM: Out[b,l,n] = scl*(sum_k A[b,l,k]*Bw[n,k] + bias[n]) ----------
// A: [B][4096][KD] bf16 row-major; Bw: [384][KD] bf16 (B^T layout); 128x128 tile, BK=64
template<int KD, bool OUT_BF16>
__global__ __launch_bounds__(256) void gemm_mfma(
    const unsigned short* __restrict__ A,
    const unsigned short* __restrict__ Bw,
    const float* __restrict__ bias,
    void* __restrict__ Out, float scl)
{
    __shared__ unsigned short As[128 * 64];
    __shared__ unsigned short Bs[128 * 64];
    const int t = threadIdx.x;
    const int lane = t & 63;
    const int w = t >> 6;
    const int wm = w >> 1, wn = w & 1;
    const int b = blockIdx.z;
    const int m0 = blockIdx.x * 128;
    const int n0 = blockIdx.y * 128;

    const unsigned short* Ab = A + ((size_t)b * LDIM + m0) * KD;
    const unsigned short* Bb = Bw + (size_t)n0 * KD;

    f4v acc[4][4];
#pragma unroll
    for (int i = 0; i < 4; ++i)
#pragma unroll
        for (int j = 0; j < 4; ++j) acc[i][j] = (f4v)0.f;

    const int r_l = lane >> 3;   // row within 8-row chunk
    const int q = lane & 7;      // 16B slot within 128B row

    for (int ks = 0; ks < KD; ks += 64) {
#pragma unroll
        for (int c = 0; c < 4; ++c) {
            int row = w * 32 + c * 8 + r_l;
            int koff = ((q ^ (row & 7)) << 3);  // swizzled source, linear LDS dest
            gload16(Ab + (size_t)row * KD + ks + koff, &As[(w * 32 + c * 8) * 64]);
            gload16(Bb + (size_t)row * KD + ks + koff, &Bs[(w * 32 + c * 8) * 64]);
        }
        __syncthreads();
#pragma unroll
        for (int kh = 0; kh < 2; ++kh) {
            s8v af[4], bfr[4];
            int kq = kh * 4 + (lane >> 4);
#pragma unroll
            for (int m = 0; m < 4; ++m) {
                int row = wm * 64 + m * 16 + (lane & 15);
                af[m] = *(const s8v*)&As[row * 64 + ((kq ^ (row & 7)) << 3)];
            }
#pragma unroll
            for (int n = 0; n < 4; ++n) {
                int row = wn * 64 + n * 16 + (lane & 15);
                bfr[n] = *(const s8v*)&Bs[row * 64 + ((kq ^ (row & 7)) << 3)];
            }
#pragma unroll
            for (int m = 0; m < 4; ++m)
#pragma unroll
                for (int n = 0; n < 4; ++n)
                    acc[m][n] = __builtin_amdgcn_mfma_f32_16x16x32_bf16(af[m], bfr[n], acc[m][n], 0, 0, 0);
        }
        __syncthreads();
    }

    float biasr[4];
#pragma unroll
    for (int n = 0; n < 4; ++n) biasr[n] = bias[n0 + wn * 64 + n * 16 + (lane & 15)];
#pragma unroll
    for (int m = 0; m < 4; ++m)
#pragma unroll
        for (int n = 0; n < 4; ++n) {
            int col = n0 + wn * 64 + n * 16 + (lane & 15);
#pragma unroll
            for (int r = 0; r < 4; ++r) {
                int row = m0 + wm * 64 + m * 16 + (lane >> 4) * 4 + r;
                float v = (acc[m][n][r] + biasr[n]) * scl;
                size_t o = ((size_t)b * LDIM + row) * ADIM + col;
                if (OUT_BF16) ((unsigned short*)Out)[o] = f2bf(v);
                else          ((float*)Out)[o] = v;
            }
        }
}

// ---------- column softmax stats over L ----------
__global__ __launch_bounds__(384) void col_partial(const float* __restrict__ K,
                                                   float* __restrict__ pm, float* __restrict__ ps)
{
    int b = blockIdx.y, ch = blockIdx.x, a = threadIdx.x;
    const int CL = LDIM / NCHUNK;
    const float* Kb = K + (size_t)b * LDIM * ADIM + (size_t)ch * CL * ADIM + a;
    float m = -1e30f;
    for (int l = 0; l < CL; ++l) m = fmaxf(m, Kb[(size_t)l * ADIM]);
    float s = 0.f;
    for (int l = 0; l < CL; ++l) s += __expf(Kb[(size_t)l * ADIM] - m);
    pm[(b * NCHUNK + ch) * ADIM + a] = m;
    ps[(b * NCHUNK + ch) * ADIM + a] = s;
}

__global__ __launch_bounds__(384) void col_combine(const float* __restrict__ pm, const float* __restrict__ ps,
                                                   float* __restrict__ fm, float* __restrict__ fs)
{
    int b = blockIdx.x, a = threadIdx.x;
    float m = -1e30f;
    for (int c = 0; c < NCHUNK; ++c) m = fmaxf(m, pm[(b * NCHUNK + c) * ADIM + a]);
    float s = 0.f;
    for (int c = 0; c < NCHUNK; ++c) s += ps[(b * NCHUNK + c) * ADIM + a] * __expf(pm[(b * NCHUNK + c) * ADIM + a] - m);
    fm[b * ADIM + a] = m;
    fs[b * ADIM + a] = s;
}

// ---------- kv[b,h,d,e] = sum_l softmax(K)[l,d] * V[l,e] ----------
__global__ __launch_bounds__(KVT) void kv_accum(const float* __restrict__ K, const float* __restrict__ V,
                                                const float* __restrict__ fm, const float* __restrict__ fs,
                                                float* __restrict__ kvg)
{
    __shared__ float Ps[64][48];
    __shared__ float Vs[64][48];
    __shared__ float ml[48], isl[48];
    int b = blockIdx.z, h = blockIdx.y, lc = blockIdx.x;
    int t = threadIdx.x;
    if (t < 48) {
        ml[t]  = fm[b * ADIM + h * DHD + t];
        isl[t] = 1.f / fs[b * ADIM + h * DHD + t];
    }
    __syncthreads();
    int d = t / 12, e4 = (t % 12) * 4;
    f4v acc = (f4v)0.f;
    int lbase = lc * (LDIM / KV_LCH);
    for (int lt = 0; lt < (LDIM / KV_LCH); lt += 64) {
        for (int idx = t; idx < 64 * 48; idx += KVT) {
            int ll = idx / 48, dd = idx % 48;
            size_t g = (size_t)b * LDIM * ADIM + (size_t)(lbase + lt + ll) * ADIM + h * DHD + dd;
            Ps[ll][dd] = __expf(K[g] - ml[dd]) * isl[dd];
            Vs[ll][dd] = V[g];
        }
        __syncthreads();
        for (int l = 0; l < 64; ++l) {
            float p = Ps[l][d];
            f4v v = *(const f4v*)&Vs[l][e4];
            acc += p * v;
        }
        __syncthreads();
    }
    float* kvb = kvg + ((size_t)b * NH + h) * DHD * DHD;
    atomicAdd(&kvb[d * DHD + e4 + 0], acc[0]);
    atomicAdd(&kvb[d * DHD + e4 + 1], acc[1]);
    atomicAdd(&kvb[d * DHD + e4 + 2], acc[2]);
    atomicAdd(&kvb[d * DHD + e4 + 3], acc[3]);
}

// ---------- kvT[b,h][e][d(pad64)] bf16 = kv[b,h][d][e] ----------
__global__ __launch_bounds__(256) void kv_transpose(const float* __restrict__ kvg,
                                                    unsigned short* __restrict__ kvT)
{
    int bh = blockIdx.x, t = threadIdx.x;
    const float* kv = kvg + (size_t)bh * DHD * DHD;
    unsigned short* o = kvT + (size_t)bh * DHD * 64;
    for (int idx = t; idx < DHD * 64; idx += 256) {
        int e = idx >> 6, dd = idx & 63;
        o[idx] = (dd < DHD) ? f2bf(kv[dd * DHD + e]) : (unsigned short)0;
    }
}

// ---------- ctx[b,l,h*48+e] = sum_d Q[b,l,h*48+d] * kvT[e][d]  (MFMA, K padded to 64) ----------
__global__ __launch_bounds__(256) void ctx_mfma(const unsigned short* __restrict__ Q,
                                                const unsigned short* __restrict__ kvT,
                                                unsigned short* __restrict__ CTX)
{
    int t = threadIdx.x, lane = t & 63, w = t >> 6;
    int b = blockIdx.z, h = blockIdx.y;
    int l0 = blockIdx.x * 256 + w * 64;
    const unsigned short* kvb = kvT + (size_t)(b * NH + h) * DHD * 64;

    s8v bfr[3][2];
#pragma unroll
    for (int n = 0; n < 3; ++n)
#pragma unroll
        for (int kh = 0; kh < 2; ++kh) {
            int e = n * 16 + (lane & 15);
            int k = kh * 32 + (lane >> 4) * 8;
            bfr[n][kh] = *(const s8v*)&kvb[e * 64 + k];
        }

    f4v acc[4][3];
#pragma unroll
    for (int m = 0; m < 4; ++m)
#pragma unroll
        for (int n = 0; n < 3; ++n) acc[m][n] = (f4v)0.f;

    const unsigned short* Qb = Q + (size_t)b * LDIM * ADIM;
#pragma unroll
    for (int m = 0; m < 4; ++m) {
        int row = l0 + m * 16 + (lane & 15);
#pragma unroll
        for (int kh = 0; kh < 2; ++kh) {
            int k = kh * 32 + (lane >> 4) * 8;
            s8v af = *(const s8v*)&Qb[(size_t)row * ADIM + h * DHD + k];
#pragma unroll
            for (int n = 0; n < 3; ++n)
                acc[m][n] = __builtin_amdgcn_mfma_f32_16x16x32_bf16(af, bfr[n][kh], acc[m][n], 0, 0, 0);
        }
    }
#pragma unroll
    for (int m = 0; m < 4; ++m)
#pragma unroll
        for (int n = 0; n < 3; ++n)
#pragma unroll
            for (int r = 0; r < 4; ++r) {
                int row = l0 + m * 16 + (lane >> 4) * 4 + r;
                int col = h * DHD + n * 16 + (lane & 15);
                CTX[((size_t)b * LDIM + row) * ADIM + col] = f2bf(acc[m][n][r]);
            }
}

// ---------- residual + LayerNorm + transpose store ----------
__global__ __launch_bounds__(256) void ln_store(const float* __restrict__ OUT, const float* __restrict__ x1,
                                                const float* __restrict__ gamma, const float* __restrict__ beta,
                                                float* __restrict__ Y)
{
    __shared__ float Ts[32][C1D + 1];
    __shared__ float mus[32], rss[32];
    int b = blockIdx.y, l0 = blockIdx.x * 32;
    int t = threadIdx.x;
    for (int idx = t; idx < 32 * C1D; idx += 256) {
        int li = idx / C1D, c = idx % C1D;
        Ts[li][c] = OUT[(size_t)b * LDIM * C1D + (size_t)(l0 + li) * C1D + c];
    }
    __syncthreads();
    for (int idx = t; idx < 32 * C1D; idx += 256) {
        int c = idx / 32, li = idx % 32;
        Ts[li][c] += x1[(size_t)b * C1D * LDIM + (size_t)c * LDIM + l0 + li];
    }
    __syncthreads();
    {
        int li = t >> 3, sub = t & 7;
        float sm = 0.f, sq = 0.f;
        for (int c = sub; c < C1D; c += 8) { float v = Ts[li][c]; sm += v; sq += v * v; }
#pragma unroll
        for (int o = 1; o < 8; o <<= 1) { sm += __shfl_xor(sm, o, 64); sq += __shfl_xor(sq, o, 64); }
        if (sub == 0) {
            float mu = sm / C1D;
            float var = sq / C1D - mu * mu;
            mus[li] = mu;
            rss[li] = rsqrtf(var + LN_EPS);
        }
    }
    __syncthreads();
    for (int idx = t; idx < 32 * C1D; idx += 256) {
        int c = idx / 32, li = idx % 32;
        float v = (Ts[li][c] - mus[li]) * rss[li] * gamma[c] + beta[c];
        Y[(size_t)b * C1D * LDIM + (size_t)c * LDIM + l0 + li] = v;
    }
}

extern "C" void kernel_launch(void* const* d_in, const int* in_sizes, int n_in,
                              void* d_out, int out_size, void* d_ws, size_t ws_size,
                              hipStream_t stream) {
    const float* x1    = (const float*)d_in[0];
    const float* x2    = (const float*)d_in[1];
    const float* Wq    = (const float*)d_in[2];
    const float* bq    = (const float*)d_in[3];
    const float* Wk    = (const float*)d_in[4];
    const float* bk    = (const float*)d_in[5];
    const float* Wv    = (const float*)d_in[6];
    const float* bv    = (const float*)d_in[7];
    const float* Wo    = (const float*)d_in[8];
    const float* bo    = (const float*)d_in[9];
    const float* gamma = (const float*)d_in[10];
    const float* beta  = (const float*)d_in[11];
    float* out = (float*)d_out;

    char* base = (char*)d_ws;
    const size_t NB = (size_t)BB * LDIM * ADIM;  // 12.58M elems
    float* Kb = (float*)base;                                  // NB f32
    float* Vb = (float*)(base + NB * 4);                       // NB f32
    unsigned short* X1p  = (unsigned short*)(base + NB * 4);   // alias Vb (dead before V-gemm writes)
    unsigned short* CTXb = (unsigned short*)(base + NB * 4);   // alias Vb (dead after kv_accum)
    char* p = base + NB * 8;
    unsigned short* Qb = (unsigned short*)p; p += NB * 2;      // bf16 Q
    unsigned short* X2p = (unsigned short*)p; p += NB;         // NB/2 bf16 elems
    unsigned short* Wqp = (unsigned short*)p; p += (size_t)C1D * ADIM * 2;
    unsigned short* Wkp = (unsigned short*)p; p += (size_t)C2D * ADIM * 2;
    unsigned short* Wvp = (unsigned short*)p; p += (size_t)C2D * ADIM * 2;
    unsigned short* Wop = (unsigned short*)p; p += (size_t)ADIM * C1D * 2;
    float* pm = (float*)p; p += (size_t)BB * NCHUNK * ADIM * 4;
    float* ps = (float*)p; p += (size_t)BB * NCHUNK * ADIM * 4;
    float* fm = (float*)p; p += (size_t)BB * ADIM * 4;
    float* fs = (float*)p; p += (size_t)BB * ADIM * 4;
    float* kvb = (float*)p; p += (size_t)BB * NH * DHD * DHD * 4;
    unsigned short* kvT = (unsigned short*)p; p += (size_t)BB * NH * DHD * 64 * 2;
    float* OUT = Kb;  // alias (K dead after kv_accum)

    float inv_scale = powf((float)DHD, -0.25f);

    // pack inputs/weights -> bf16, K-contiguous
    transpose_cvt<<<dim3(LDIM / 32, C1D / 32, BB), 256, 0, stream>>>(x1, X1p, C1D, LDIM);
    transpose_cvt<<<dim3(LDIM / 32, C2D / 32, BB), 256, 0, stream>>>(x2, X2p, C2D, LDIM);
    transpose_cvt<<<dim3(ADIM / 32, C1D / 32, 1), 256, 0, stream>>>(Wq, Wqp, C1D, ADIM);
    transpose_cvt<<<dim3(ADIM / 32, C2D / 32, 1), 256, 0, stream>>>(Wk, Wkp, C2D, ADIM);
    transpose_cvt<<<dim3(ADIM / 32, C2D / 32, 1), 256, 0, stream>>>(Wv, Wvp, C2D, ADIM);
    transpose_cvt<<<dim3(C1D / 32, ADIM / 32, 1), 256, 0, stream>>>(Wo, Wop, ADIM, C1D);

    dim3 gg(LDIM / 128, ADIM / 128, BB);
    gemm_mfma<C1D, true ><<<gg, 256, 0, stream>>>(X1p, Wqp, bq, Qb, inv_scale);
    gemm_mfma<C2D, false><<<gg, 256, 0, stream>>>(X2p, Wkp, bk, Kb, inv_scale);
    gemm_mfma<C2D, false><<<gg, 256, 0, stream>>>(X2p, Wvp, bv, Vb, 1.0f);

    col_partial<<<dim3(NCHUNK, BB), 384, 0, stream>>>(Kb, pm, ps);
    col_combine<<<BB, 384, 0, stream>>>(pm, ps, fm, fs);

    hipMemsetAsync(kvb, 0, (size_t)BB * NH * DHD * DHD * sizeof(float), stream);
    kv_accum<<<dim3(KV_LCH, NH, BB), KVT, 0, stream>>>(Kb, Vb, fm, fs, kvb);
    kv_transpose<<<BB * NH, 256, 0, stream>>>(kvb, kvT);

    ctx_mfma<<<dim3(LDIM / 256, NH, BB), 256, 0, stream>>>(Qb, kvT, CTXb);
    gemm_mfma<C1D, false><<<gg, 256, 0, stream>>>(CTXb, Wop, bo, OUT, 1.0f);
    ln_store<<<dim3(LDIM / 32, BB), 256, 0, stream>>>(OUT, x1, gamma, beta, out);
}

// Round 5
// 170.985 us; speedup vs baseline: 3.8416x; 1.5568x over previous
//
#include <hip/hip_runtime.h>
#include <hip/hip_bf16.h>
#include <math.h>

#define BB 8
#define C1D 384
#define C2D 192
#define LDIM 4096
#define ADIM 384
#define NH 8
#define DHD 48
#define KVLC 16
#define LN_EPS 1e-5f

typedef short s8v __attribute__((ext_vector_type(8)));
typedef float f4v __attribute__((ext_vector_type(4)));

__device__ __forceinline__ unsigned short f2bf(float f) {
    unsigned u = __builtin_bit_cast(unsigned, f);
    unsigned r = (u + 0x7FFFu + ((u >> 16) & 1u)) >> 16;
    return (unsigned short)r;
}
__device__ __forceinline__ float bf2f(unsigned short h) {
    unsigned u = ((unsigned)h) << 16;
    return __builtin_bit_cast(float, u);
}
__device__ __forceinline__ void gload16(const void* g, void* l) {
    __builtin_amdgcn_global_load_lds((const __attribute__((address_space(1))) void*)g,
                                     (__attribute__((address_space(3))) void*)l, 16, 0, 0);
}

// ---------- transpose fp32 [bz][R][Cols] -> bf16 [bz][Cols][R] ----------
__global__ __launch_bounds__(256) void transpose_cvt(const float* __restrict__ in,
                                                     unsigned short* __restrict__ out,
                                                     int R, int Cols)
{
    __shared__ float T[32][33];
    int b = blockIdx.z;
    int c0 = blockIdx.x * 32, r0 = blockIdx.y * 32;
    const float* ib = in + (size_t)b * R * Cols;
    unsigned short* ob = out + (size_t)b * R * Cols;
    int t = threadIdx.x;
#pragma unroll
    for (int i = 0; i < 4; ++i) {
        int idx = t + i * 256;
        int rr = idx >> 5, cc = idx & 31;
        T[rr][cc] = ib[(size_t)(r0 + rr) * Cols + c0 + cc];
    }
    __syncthreads();
#pragma unroll
    for (int i = 0; i < 2; ++i) {
        int idx = t + i * 256;
        int cc = idx >> 4, rp = (idx & 15) * 2;
        unsigned val = (unsigned)f2bf(T[rp][cc]) | ((unsigned)f2bf(T[rp + 1][cc]) << 16);
        *(unsigned*)&ob[(size_t)(c0 + cc) * R + r0 + rp] = val;
    }
}

// ---------- bf16 MFMA GEMM: Out[b,m,n] = scl*(sum_k A[b,m,k]*Bt[b,n,k] + bias) ----------
template<int KD, bool OUT_BF16, bool BIAS_M>
__global__ __launch_bounds__(256) void gemm_mfma(
    const unsigned short* __restrict__ A, size_t Abs,
    const unsigned short* __restrict__ Bt, size_t Bbs,
    const float* __restrict__ bias,
    void* __restrict__ Out, size_t Obs, int Ncols, float scl)
{
    __shared__ unsigned short As[128 * 64];
    __shared__ unsigned short Bs[128 * 64];
    const int t = threadIdx.x;
    const int lane = t & 63;
    const int w = t >> 6;
    const int wm = w >> 1, wn = w & 1;
    const int b = blockIdx.z;
    const int m0 = blockIdx.x * 128;
    const int n0 = blockIdx.y * 128;

    const unsigned short* Ab = A + Abs * b + (size_t)m0 * KD;
    const unsigned short* Bb = Bt + Bbs * b + (size_t)n0 * KD;

    f4v acc[4][4];
#pragma unroll
    for (int i = 0; i < 4; ++i)
#pragma unroll
        for (int j = 0; j < 4; ++j) acc[i][j] = (f4v)0.f;

    const int r_l = lane >> 3;
    const int q = lane & 7;

    for (int ks = 0; ks < KD; ks += 64) {
#pragma unroll
        for (int c = 0; c < 4; ++c) {
            int row = w * 32 + c * 8 + r_l;
            int koff = ((q ^ (row & 7)) << 3);
            gload16(Ab + (size_t)row * KD + ks + koff, &As[(w * 32 + c * 8) * 64]);
            gload16(Bb + (size_t)row * KD + ks + koff, &Bs[(w * 32 + c * 8) * 64]);
        }
        __syncthreads();
#pragma unroll
        for (int kh = 0; kh < 2; ++kh) {
            s8v af[4], bfr[4];
            int kq = kh * 4 + (lane >> 4);
#pragma unroll
            for (int m = 0; m < 4; ++m) {
                int row = wm * 64 + m * 16 + (lane & 15);
                af[m] = *(const s8v*)&As[row * 64 + ((kq ^ (row & 7)) << 3)];
            }
#pragma unroll
            for (int n = 0; n < 4; ++n) {
                int row = wn * 64 + n * 16 + (lane & 15);
                bfr[n] = *(const s8v*)&Bs[row * 64 + ((kq ^ (row & 7)) << 3)];
            }
#pragma unroll
            for (int m = 0; m < 4; ++m)
#pragma unroll
                for (int n = 0; n < 4; ++n)
                    acc[m][n] = __builtin_amdgcn_mfma_f32_16x16x32_bf16(af[m], bfr[n], acc[m][n], 0, 0, 0);
        }
        __syncthreads();
    }

    float bn[4], bm[4][4];
    if (BIAS_M) {
#pragma unroll
        for (int m = 0; m < 4; ++m)
#pragma unroll
            for (int r = 0; r < 4; ++r)
                bm[m][r] = bias[m0 + wm * 64 + m * 16 + (lane >> 4) * 4 + r];
    } else {
#pragma unroll
        for (int n = 0; n < 4; ++n) bn[n] = bias[n0 + wn * 64 + n * 16 + (lane & 15)];
    }
#pragma unroll
    for (int m = 0; m < 4; ++m)
#pragma unroll
        for (int n = 0; n < 4; ++n) {
            int col = n0 + wn * 64 + n * 16 + (lane & 15);
#pragma unroll
            for (int r = 0; r < 4; ++r) {
                int row = m0 + wm * 64 + m * 16 + (lane >> 4) * 4 + r;
                float bb = BIAS_M ? bm[m][r] : bn[n];
                float v = (acc[m][n][r] + bb) * scl;
                size_t o = Obs * b + (size_t)row * Ncols + col;
                if (OUT_BF16) ((unsigned short*)Out)[o] = f2bf(v);
                else          ((float*)Out)[o] = v;
            }
        }
}

// ---------- per-row sum(exp(.)) over L of Kt, store 1/s ----------
__global__ __launch_bounds__(256) void k_stats(const unsigned short* __restrict__ Kt,
                                               float* __restrict__ isl)
{
    int w = threadIdx.x >> 6, lane = threadIdx.x & 63;
    int r = blockIdx.x * 4 + w;  // b*384 + a
    const unsigned short* p = Kt + (size_t)r * LDIM;
    float s = 0.f;
#pragma unroll
    for (int i = 0; i < 8; ++i) {
        s8v v = *(const s8v*)&p[(i * 64 + lane) * 8];
#pragma unroll
        for (int j = 0; j < 8; ++j) s += __expf(bf2f((unsigned short)v[j]));
    }
#pragma unroll
    for (int o = 1; o < 64; o <<= 1) s += __shfl_xor(s, o, 64);
    if (lane == 0) isl[r] = 1.f / s;
}

// ---------- kvpart[bh][lc][e*48+d] = sum_{l in chunk} Vt[e][l]*exp(Kt[d][l]) ----------
__global__ __launch_bounds__(64) void kv_part(const unsigned short* __restrict__ Kt,
                                              const unsigned short* __restrict__ Vt,
                                              float* __restrict__ kvpart)
{
    int lane = threadIdx.x;
    int b = blockIdx.z, h = blockIdx.y, lc = blockIdx.x;
    size_t base = ((size_t)b * ADIM + h * DHD) * LDIM;
    const unsigned short* Kb = Kt + base;
    const unsigned short* Vb = Vt + base;
    int lbase = lc * (LDIM / KVLC);

    f4v acc[3][3];
#pragma unroll
    for (int i = 0; i < 3; ++i)
#pragma unroll
        for (int j = 0; j < 3; ++j) acc[i][j] = (f4v)0.f;

    for (int ks = 0; ks < LDIM / KVLC; ks += 32) {
        int l0 = lbase + ks + ((lane >> 4) * 8);
        s8v af[3], bfr[3];
#pragma unroll
        for (int me = 0; me < 3; ++me)
            af[me] = *(const s8v*)&Vb[(size_t)(me * 16 + (lane & 15)) * LDIM + l0];
#pragma unroll
        for (int nd = 0; nd < 3; ++nd) {
            s8v raw = *(const s8v*)&Kb[(size_t)(nd * 16 + (lane & 15)) * LDIM + l0];
#pragma unroll
            for (int j = 0; j < 8; ++j)
                bfr[nd][j] = (short)f2bf(__expf(bf2f((unsigned short)raw[j])));
        }
#pragma unroll
        for (int me = 0; me < 3; ++me)
#pragma unroll
            for (int nd = 0; nd < 3; ++nd)
                acc[me][nd] = __builtin_amdgcn_mfma_f32_16x16x32_bf16(af[me], bfr[nd], acc[me][nd], 0, 0, 0);
    }
    float* pp = kvpart + (((size_t)(b * NH + h) * KVLC) + lc) * (DHD * DHD);
#pragma unroll
    for (int me = 0; me < 3; ++me)
#pragma unroll
        for (int nd = 0; nd < 3; ++nd)
#pragma unroll
            for (int r = 0; r < 4; ++r) {
                int e = me * 16 + (lane >> 4) * 4 + r;   // C/D row
                int d = nd * 16 + (lane & 15);           // C/D col
                pp[e * DHD + d] = acc[me][nd][r];
            }
}

// ---------- kvT bf16 [bh][e][64] = (sum_lc kvpart)[e][d]*isl[d], zero-padded ----------
__global__ __launch_bounds__(256) void kv_finalize(const float* __restrict__ kvpart,
                                                   const float* __restrict__ isl,
                                                   unsigned short* __restrict__ kvT)
{
    int bh = blockIdx.x, b = bh >> 3, h = bh & 7, t = threadIdx.x;
    const float* pp = kvpart + (size_t)bh * KVLC * DHD * DHD;
    unsigned short* o = kvT + (size_t)bh * DHD * 64;
    for (int idx = t; idx < DHD * 64; idx += 256) {
        int e = idx >> 6, dd = idx & 63;
        float v = 0.f;
        if (dd < DHD) {
            float s = 0.f;
#pragma unroll
            for (int lc = 0; lc < KVLC; ++lc) s += pp[lc * DHD * DHD + e * DHD + dd];
            v = s * isl[b * ADIM + h * DHD + dd];
        }
        o[idx] = f2bf(v);
    }
}

// ---------- ctx[b,l,h*48+e] = sum_d Q[b,l,h*48+d] * kvT[e][d] ----------
__global__ __launch_bounds__(256) void ctx_mfma(const unsigned short* __restrict__ Q,
                                                const unsigned short* __restrict__ kvT,
                                                unsigned short* __restrict__ CTX)
{
    int t = threadIdx.x, lane = t & 63, w = t >> 6;
    int b = blockIdx.z, h = blockIdx.y;
    int l0 = blockIdx.x * 256 + w * 64;
    const unsigned short* kvb = kvT + (size_t)(b * NH + h) * DHD * 64;

    s8v bfr[3][2];
#pragma unroll
    for (int n = 0; n < 3; ++n)
#pragma unroll
        for (int kh = 0; kh < 2; ++kh) {
            int e = n * 16 + (lane & 15);
            int k = kh * 32 + (lane >> 4) * 8;
            bfr[n][kh] = *(const s8v*)&kvb[e * 64 + k];
        }

    f4v acc[4][3];
#pragma unroll
    for (int m = 0; m < 4; ++m)
#pragma unroll
        for (int n = 0; n < 3; ++n) acc[m][n] = (f4v)0.f;

    const unsigned short* Qb = Q + (size_t)b * LDIM * ADIM;
#pragma unroll
    for (int m = 0; m < 4; ++m) {
        int row = l0 + m * 16 + (lane & 15);
#pragma unroll
        for (int kh = 0; kh < 2; ++kh) {
            int k = kh * 32 + (lane >> 4) * 8;
            s8v af = *(const s8v*)&Qb[(size_t)row * ADIM + h * DHD + k];
#pragma unroll
            for (int n = 0; n < 3; ++n)
                acc[m][n] = __builtin_amdgcn_mfma_f32_16x16x32_bf16(af, bfr[n][kh], acc[m][n], 0, 0, 0);
        }
    }
#pragma unroll
    for (int m = 0; m < 4; ++m)
#pragma unroll
        for (int n = 0; n < 3; ++n)
#pragma unroll
            for (int r = 0; r < 4; ++r) {
                int row = l0 + m * 16 + (lane >> 4) * 4 + r;
                int col = h * DHD + n * 16 + (lane & 15);
                CTX[((size_t)b * LDIM + row) * ADIM + col] = f2bf(acc[m][n][r]);
            }
}

// ---------- residual + LayerNorm + transpose store ----------
__global__ __launch_bounds__(256) void ln_store(const unsigned short* __restrict__ OUT,
                                                const float* __restrict__ x1,
                                                const float* __restrict__ gamma, const float* __restrict__ beta,
                                                float* __restrict__ Y)
{
    __shared__ float Ts[32][C1D + 1];
    __shared__ float mus[32], rss[32];
    int b = blockIdx.y, l0 = blockIdx.x * 32;
    int t = threadIdx.x;
    for (int idx = t; idx < 32 * C1D; idx += 256) {
        int li = idx / C1D, c = idx % C1D;
        Ts[li][c] = bf2f(OUT[(size_t)b * LDIM * C1D + (size_t)(l0 + li) * C1D + c]);
    }
    __syncthreads();
    for (int idx = t; idx < 32 * C1D; idx += 256) {
        int c = idx / 32, li = idx % 32;
        Ts[li][c] += x1[(size_t)b * C1D * LDIM + (size_t)c * LDIM + l0 + li];
    }
    __syncthreads();
    {
        int li = t >> 3, sub = t & 7;
        float sm = 0.f, sq = 0.f;
        for (int c = sub; c < C1D; c += 8) { float v = Ts[li][c]; sm += v; sq += v * v; }
#pragma unroll
        for (int o = 1; o < 8; o <<= 1) { sm += __shfl_xor(sm, o, 64); sq += __shfl_xor(sq, o, 64); }
        if (sub == 0) {
            float mu = sm / C1D;
            float var = sq / C1D - mu * mu;
            mus[li] = mu;
            rss[li] = rsqrtf(var + LN_EPS);
        }
    }
    __syncthreads();
    for (int idx = t; idx < 32 * C1D; idx += 256) {
        int c = idx / 32, li = idx % 32;
        float v = (Ts[li][c] - mus[li]) * rss[li] * gamma[c] + beta[c];
        Y[(size_t)b * C1D * LDIM + (size_t)c * LDIM + l0 + li] = v;
    }
}

extern "C" void kernel_launch(void* const* d_in, const int* in_sizes, int n_in,
                              void* d_out, int out_size, void* d_ws, size_t ws_size,
                              hipStream_t stream) {
    const float* x1    = (const float*)d_in[0];
    const float* x2    = (const float*)d_in[1];
    const float* Wq    = (const float*)d_in[2];
    const float* bq    = (const float*)d_in[3];
    const float* Wk    = (const float*)d_in[4];
    const float* bk    = (const float*)d_in[5];
    const float* Wv    = (const float*)d_in[6];
    const float* bv    = (const float*)d_in[7];
    const float* Wo    = (const float*)d_in[8];
    const float* bo    = (const float*)d_in[9];
    const float* gamma = (const float*)d_in[10];
    const float* beta  = (const float*)d_in[11];
    float* out = (float*)d_out;

    char* p = (char*)d_ws;
    const size_t NB  = (size_t)BB * LDIM * ADIM;   // whole-tensor elems
    const size_t PBS = (size_t)LDIM * ADIM;        // PER-BATCH stride (the round-3 bug: passed NB here)
    unsigned short* X1p = (unsigned short*)p; p += NB * 2;
    unsigned short* X2p = (unsigned short*)p; p += NB;           // NB/2 elems
    unsigned short* Qb  = (unsigned short*)p; p += NB * 2;
    unsigned short* Kt  = (unsigned short*)p; p += NB * 2;
    unsigned short* Vt  = (unsigned short*)p; p += NB * 2;
    unsigned short* OUTb= (unsigned short*)p; p += NB * 2;
    unsigned short* Wqp = (unsigned short*)p; p += (size_t)C1D * ADIM * 2;
    unsigned short* Wkp = (unsigned short*)p; p += (size_t)C2D * ADIM * 2;
    unsigned short* Wvp = (unsigned short*)p; p += (size_t)C2D * ADIM * 2;
    unsigned short* Wop = (unsigned short*)p; p += (size_t)ADIM * C1D * 2;
    float* isl    = (float*)p; p += (size_t)BB * ADIM * 4;
    float* kvpart = (float*)p; p += (size_t)BB * NH * KVLC * DHD * DHD * 4;
    unsigned short* kvT = (unsigned short*)p; p += (size_t)BB * NH * DHD * 64 * 2;
    unsigned short* CTXb = X1p;  // X1p dead after Q-GEMM

    float inv_scale = powf((float)DHD, -0.25f);

    transpose_cvt<<<dim3(LDIM / 32, C1D / 32, BB), 256, 0, stream>>>(x1, X1p, C1D, LDIM);
    transpose_cvt<<<dim3(LDIM / 32, C2D / 32, BB), 256, 0, stream>>>(x2, X2p, C2D, LDIM);
    transpose_cvt<<<dim3(ADIM / 32, C1D / 32, 1), 256, 0, stream>>>(Wq, Wqp, C1D, ADIM);
    transpose_cvt<<<dim3(ADIM / 32, C2D / 32, 1), 256, 0, stream>>>(Wk, Wkp, C2D, ADIM);
    transpose_cvt<<<dim3(ADIM / 32, C2D / 32, 1), 256, 0, stream>>>(Wv, Wvp, C2D, ADIM);
    transpose_cvt<<<dim3(C1D / 32, ADIM / 32, 1), 256, 0, stream>>>(Wo, Wop, ADIM, C1D);

    // Q[b,l,a]
    gemm_mfma<C1D, true, false><<<dim3(LDIM / 128, ADIM / 128, BB), 256, 0, stream>>>(
        X1p, (size_t)LDIM * C1D, Wqp, 0, bq, Qb, PBS, ADIM, inv_scale);
    // Kt[b,a,l], Vt[b,a,l]
    gemm_mfma<C2D, true, true><<<dim3(ADIM / 128, LDIM / 128, BB), 256, 0, stream>>>(
        Wkp, 0, X2p, (size_t)LDIM * C2D, bk, Kt, PBS, LDIM, inv_scale);
    gemm_mfma<C2D, true, true><<<dim3(ADIM / 128, LDIM / 128, BB), 256, 0, stream>>>(
        Wvp, 0, X2p, (size_t)LDIM * C2D, bv, Vt, PBS, LDIM, 1.0f);

    k_stats<<<(BB * ADIM) / 4, 256, 0, stream>>>(Kt, isl);

    kv_part<<<dim3(KVLC, NH, BB), 64, 0, stream>>>(Kt, Vt, kvpart);
    kv_finalize<<<BB * NH, 256, 0, stream>>>(kvpart, isl, kvT);

    ctx_mfma<<<dim3(LDIM / 256, NH, BB), 256, 0, stream>>>(Qb, kvT, CTXb);
    gemm_mfma<C1D, true, false><<<dim3(LDIM / 128, ADIM / 128, BB), 256, 0, stream>>>(
        CTXb, (size_t)LDIM * ADIM, Wop, 0, bo, OUTb, PBS, ADIM, 1.0f);
    ln_store<<<dim3(LDIM / 32, BB), 256, 0, stream>>>(OUTb, x1, gamma, beta, out);
}